// Round 11
// baseline (5561.266 us; speedup 1.0000x reference)
//
#include <hip/hip_runtime.h>
#include <hip/hip_bf16.h>
#include <math.h>

#define NV 50000
#define NE 256
#define NH 256
#define NT 20
#define NB 64
#define NL 512
#define TAG_START 18
#define TAG_STOP 19
#define NEGV -10000.0f

typedef unsigned short ushortT;
typedef __attribute__((ext_vector_type(4))) float f32x4;
typedef __attribute__((ext_vector_type(8))) short short8;
typedef __attribute__((ext_vector_type(4))) unsigned short us4;

#define PINV(x) asm volatile("" : "+v"(x))

__device__ __forceinline__ float sigf_slow(float x) { return 1.0f / (1.0f + expf(-x)); }
__device__ __forceinline__ float fsig(float x) { return 1.0f / (1.0f + __expf(-x)); }
__device__ __forceinline__ float ftanh(float x) { return 1.0f - 2.0f / (1.0f + __expf(2.0f * x)); }
__device__ __forceinline__ ushortT f2bf(float f) {
    unsigned int u = __float_as_uint(f);
    u += 0x7fffu + ((u >> 16) & 1u);
    return (ushortT)(u >> 16);
}
__device__ __forceinline__ float bf2f(unsigned int bits16) {
    return __uint_as_float(bits16 << 16);
}

// ---- weight load into literal AGPRs ---------------------------------------
#define WRW(A0,A1,A2,A3,PTR) do {                                   \
    int4 _u = *(const int4*)(PTR);                                  \
    asm volatile("v_accvgpr_write_b32 a" #A0 ", %0\n\t"             \
                 "v_accvgpr_write_b32 a" #A1 ", %1\n\t"             \
                 "v_accvgpr_write_b32 a" #A2 ", %2\n\t"             \
                 "v_accvgpr_write_b32 a" #A3 ", %3"                 \
                 :: "v"(_u.x), "v"(_u.y), "v"(_u.z), "v"(_u.w)      \
                 : "a" #A0, "a" #A1, "a" #A2, "a" #A3);             \
} while (0)

// MFMA with B in literal AGPR range, acc in VGPRs
#define MFMA_AG(ACC, AF, A0,A1,A2,A3)                                           \
    asm volatile("v_mfma_f32_16x16x32_bf16 %0, %1, a[" #A0 ":" #A3 "], %0"      \
                 : "+v"(ACC) : "v"(AF) : "a" #A0, "a" #A1, "a" #A2, "a" #A3)

// MFMA with B in VGPRs (streamed weight)
#define MFMA_SV(ACC, AF, BW)                                                    \
    asm volatile("v_mfma_f32_16x16x32_bf16 %0, %1, %2, %0"                      \
                 : "+v"(ACC) : "v"(AF), "v"(BW))

// one k-tile: A-frag from LDS, 4 AGPR-B MFMAs (gates i,f) + 4 streamed (g,o)
#define KT_BLOCK(KT, I0a,I0b,I0c,I0d, I1a,I1b,I1c,I1d, F0a,F0b,F0c,F0d, F1a,F1b,F1c,F1d) \
    {                                                                                     \
        int a_ = (lr * 512 + (KT) * 64 + lg * 16) ^ ((lr & 7) << 4);                      \
        short8 af = *(const short8*)&hb[a_];                                              \
        MFMA_AG(acc0, af, I0a,I0b,I0c,I0d);                                               \
        MFMA_AG(acc1, af, I1a,I1b,I1c,I1d);                                               \
        MFMA_AG(acc2, af, F0a,F0b,F0c,F0d);                                               \
        MFMA_AG(acc3, af, F1a,F1b,F1c,F1d);                                               \
        MFMA_SV(acc4, af, wg0[KT]);                                                       \
        MFMA_SV(acc5, af, wg1[KT]);                                                       \
        MFMA_SV(acc6, af, wo0[KT]);                                                       \
        MFMA_SV(acc7, af, wo1[KT]);                                                       \
    }

#define BARRIER_LGKM() asm volatile("s_waitcnt lgkmcnt(0)\n\ts_barrier" ::: "memory")

// ===========================================================================
// FAST PATH
// ===========================================================================

__global__ __launch_bounds__(256) void k_cvtw(
    const float* __restrict__ whh_f, const float* __restrict__ whh_b,
    const float* __restrict__ wih_f, const float* __restrict__ wih_b,
    ushortT* __restrict__ whh16, ushortT* __restrict__ wih16)
{
    int idx = blockIdx.x * 256 + threadIdx.x;     // < 262144
    const float* s; ushortT* d;
    switch (blockIdx.y) {
        case 0: s = whh_f; d = whh16;            break;
        case 1: s = whh_b; d = whh16 + 262144;   break;
        case 2: s = wih_f; d = wih16;            break;
        default: s = wih_b; d = wih16 + 262144;  break;
    }
    d[idx] = f2bf(s[idx]);
}

__global__ __launch_bounds__(1024) void k_bias(
    const float* __restrict__ bih_f, const float* __restrict__ bhh_f,
    const float* __restrict__ bih_b, const float* __restrict__ bhh_b,
    float* __restrict__ biasc)
{
    int n = threadIdx.x;
    if (blockIdx.x == 0) biasc[n] = bih_f[n] + bhh_f[n];
    else                 biasc[1024 + n] = bih_b[n] + bhh_b[n];
}

// K-gin: gin16[dirg][t][col*16 + row] = bf16(x_t @ Wih^T + bias)
__global__
__attribute__((amdgpu_flat_work_group_size(512, 512)))
__attribute__((amdgpu_waves_per_eu(2, 2)))
void k_gin_mfma(
    const int* __restrict__ sent, const int* __restrict__ lens,
    const float* __restrict__ emb, const ushortT* __restrict__ wih16,
    const float* __restrict__ biasc, ushortT* __restrict__ gin16,
    int chunk_start, int CH)
{
    const int g = blockIdx.x, tsub = blockIdx.y;
    const int dir = blockIdx.z >> 1, half = blockIdx.z & 1;
    const int gmax = lens[g * 16];
    const int tt0 = tsub * 16;
    if (chunk_start + tt0 >= gmax) return;

    const int tid = threadIdx.x;
    const int w = tid >> 6, l = tid & 63, lr = l & 15, lg = l >> 4;

    __shared__ char x_raw[16 * 512];

    const int ucol = half * 128 + w * 16 + lr;
    short8 bfr[4][8];
    float bias_l[4];
    const ushortT* wsrc = wih16 + dir * 262144;
#pragma unroll
    for (int nt = 0; nt < 4; ++nt) {
        int col = nt * 256 + ucol;
        bias_l[nt] = biasc[dir * 1024 + col];
#pragma unroll
        for (int kt = 0; kt < 8; ++kt)
            bfr[nt][kt] = *(const short8*)(wsrc + (size_t)col * 256 + kt * 32 + lg * 8);
    }
#pragma unroll
    for (int nt = 0; nt < 4; ++nt) {
        PINV(bias_l[nt]);
#pragma unroll
        for (int kt = 0; kt < 8; ++kt) PINV(bfr[nt][kt]);
    }

    const int srow = tid >> 5, sseg = tid & 31;
    const int slen = lens[g * 16 + srow];
    const int sb = (g * 16 + srow) * 512;

    for (int i = 0; i < 16; ++i) {
        int tg = chunk_start + tt0 + i;
        if (tg >= gmax) break;

        int tsrc = dir ? (slen - 1 - tg) : tg;
        if (tsrc < 0) tsrc = 0;
        if (tsrc > 511) tsrc = 511;
        int tok = sent[sb + tsrc];
        const float* es = emb + (size_t)tok * 256 + sseg * 8;
        float4 e0 = *(const float4*)es;
        float4 e1 = *(const float4*)(es + 4);
        short8 xv;
        xv[0] = (short)f2bf(e0.x); xv[1] = (short)f2bf(e0.y);
        xv[2] = (short)f2bf(e0.z); xv[3] = (short)f2bf(e0.w);
        xv[4] = (short)f2bf(e1.x); xv[5] = (short)f2bf(e1.y);
        xv[6] = (short)f2bf(e1.z); xv[7] = (short)f2bf(e1.w);
        int sa = (srow * 512 + sseg * 16) ^ ((srow & 7) << 4);
        *(short8*)&x_raw[sa] = xv;
        __syncthreads();

        short8 af[8];
#pragma unroll
        for (int kt = 0; kt < 8; ++kt) {
            int a = (lr * 512 + kt * 64 + lg * 16) ^ ((lr & 7) << 4);
            af[kt] = *(const short8*)&x_raw[a];
        }
        f32x4 acc[4];
#pragma unroll
        for (int nt = 0; nt < 4; ++nt) {
            acc[nt][0] = bias_l[nt]; acc[nt][1] = bias_l[nt];
            acc[nt][2] = bias_l[nt]; acc[nt][3] = bias_l[nt];
        }
#pragma unroll
        for (int kt = 0; kt < 8; ++kt)
#pragma unroll
            for (int nt = 0; nt < 4; ++nt)
                acc[nt] = __builtin_amdgcn_mfma_f32_16x16x32_bf16(af[kt], bfr[nt][kt], acc[nt], 0, 0, 0);

        ushortT* gp = gin16 + ((size_t)((dir * 4 + g) * CH + (tt0 + i))) * 16384;
#pragma unroll
        for (int nt = 0; nt < 4; ++nt) {
            int col = nt * 256 + ucol;
            us4 st;
            st[0] = f2bf(acc[nt][0]); st[1] = f2bf(acc[nt][1]);
            st[2] = f2bf(acc[nt][2]); st[3] = f2bf(acc[nt][3]);
            *(us4*)(gp + col * 16 + lg * 4) = st;
        }
        __syncthreads();
    }
}

// K-rec v4: ONE WG (512 thr, 8 waves) per (group,dir). NO cross-CU exchange.
//   Gates i,f resident in AGPR a0-a127 (256 KB/WG); gates g,o streamed from
//   L2 each step; gin in bf16. One lgkm-only barrier per step.
__global__
__attribute__((amdgpu_flat_work_group_size(512, 512)))
__attribute__((amdgpu_waves_per_eu(2, 2)))
void k_rec_mfma(
    const int* __restrict__ lens, const ushortT* __restrict__ whh16,
    const ushortT* __restrict__ gin16, ushortT* __restrict__ hout,
    ushortT* __restrict__ st_h, float* __restrict__ st_c,
    int chunk_start, int CH)
{
    const int g = blockIdx.x, dir = blockIdx.y;
    const int gmax = lens[g * 16];
    const int nsteps = min(CH, gmax - chunk_start);
    if (nsteps <= 0) return;

    const int tid = threadIdx.x;
    const int w = tid >> 6, l = tid & 63, lr = l & 15, lg = l >> 4;
    const int dirg = dir * 4 + g;

    __shared__ char h_s[2][8192];   // [buf][row*512B + unit*2B], XOR-swizzled

    int lenr[4];
#pragma unroll
    for (int r = 0; r < 4; ++r) lenr[r] = lens[g * 16 + lg * 4 + r];

    const ushortT* wsrc = whh16 + dir * 262144;
    const int u0 = w * 32 + lr, u1 = w * 32 + 16 + lr;

    // ---- AGPR weights: gates i,f for units u0,u1 --------------------------
    {
        const ushortT* qi0 = wsrc + (size_t)(0   + u0) * 256 + lg * 8;
        const ushortT* qi1 = wsrc + (size_t)(0   + u1) * 256 + lg * 8;
        const ushortT* qf0 = wsrc + (size_t)(256 + u0) * 256 + lg * 8;
        const ushortT* qf1 = wsrc + (size_t)(256 + u1) * 256 + lg * 8;
        WRW(  0,  1,  2,  3, qi0 +   0); WRW(  4,  5,  6,  7, qi0 +  32);
        WRW(  8,  9, 10, 11, qi0 +  64); WRW( 12, 13, 14, 15, qi0 +  96);
        WRW( 16, 17, 18, 19, qi0 + 128); WRW( 20, 21, 22, 23, qi0 + 160);
        WRW( 24, 25, 26, 27, qi0 + 192); WRW( 28, 29, 30, 31, qi0 + 224);
        WRW( 32, 33, 34, 35, qi1 +   0); WRW( 36, 37, 38, 39, qi1 +  32);
        WRW( 40, 41, 42, 43, qi1 +  64); WRW( 44, 45, 46, 47, qi1 +  96);
        WRW( 48, 49, 50, 51, qi1 + 128); WRW( 52, 53, 54, 55, qi1 + 160);
        WRW( 56, 57, 58, 59, qi1 + 192); WRW( 60, 61, 62, 63, qi1 + 224);
        WRW( 64, 65, 66, 67, qf0 +   0); WRW( 68, 69, 70, 71, qf0 +  32);
        WRW( 72, 73, 74, 75, qf0 +  64); WRW( 76, 77, 78, 79, qf0 +  96);
        WRW( 80, 81, 82, 83, qf0 + 128); WRW( 84, 85, 86, 87, qf0 + 160);
        WRW( 88, 89, 90, 91, qf0 + 192); WRW( 92, 93, 94, 95, qf0 + 224);
        WRW( 96, 97, 98, 99, qf1 +   0); WRW(100,101,102,103, qf1 +  32);
        WRW(104,105,106,107, qf1 +  64); WRW(108,109,110,111, qf1 +  96);
        WRW(112,113,114,115, qf1 + 128); WRW(116,117,118,119, qf1 + 160);
        WRW(120,121,122,123, qf1 + 192); WRW(124,125,126,127, qf1 + 224);
        asm volatile("s_nop 1");
    }

    // streamed weight base pointers (gates g,o)
    const ushortT* pg0 = wsrc + (size_t)(512 + u0) * 256 + lg * 8;
    const ushortT* pg1 = wsrc + (size_t)(512 + u1) * 256 + lg * 8;
    const ushortT* po0 = wsrc + (size_t)(768 + u0) * 256 + lg * 8;
    const ushortT* po1 = wsrc + (size_t)(768 + u1) * 256 + lg * 8;

    // ---- state init / restore --------------------------------------------
    float c[2][4];
    if (chunk_start == 0) {
#pragma unroll
        for (int s = 0; s < 2; ++s)
#pragma unroll
            for (int r = 0; r < 4; ++r) c[s][r] = 0.0f;
        for (int i = tid; i < 2048; i += 512) ((int*)h_s[0])[i] = 0;
    } else {
        const float* cs = st_c + ((size_t)dirg * 512 + tid) * 8;
#pragma unroll
        for (int s = 0; s < 2; ++s)
#pragma unroll
            for (int r = 0; r < 4; ++r) c[s][r] = cs[s * 4 + r];
        const int* hs = (const int*)st_h + dirg * 2048;
        for (int i = tid; i < 2048; i += 512) ((int*)h_s[0])[i] = hs[i];
    }
    __syncthreads();

    const ushortT* ginp = gin16 + (size_t)dirg * CH * 16384;

    int p = 0;
    for (int tt = 0; tt < nsteps; ++tt) {
        const int t_glob = chunk_start + tt;

        // gin (bf16) for 8 (gate,unit) cols; consumed in pointwise
        const ushortT* gb = ginp + (size_t)tt * 16384 + lg * 4;
        us4 gvi0 = *(const us4*)(gb + (0   + u0) * 16);
        us4 gvi1 = *(const us4*)(gb + (0   + u1) * 16);
        us4 gvf0 = *(const us4*)(gb + (256 + u0) * 16);
        us4 gvf1 = *(const us4*)(gb + (256 + u1) * 16);
        us4 gvg0 = *(const us4*)(gb + (512 + u0) * 16);
        us4 gvg1 = *(const us4*)(gb + (512 + u1) * 16);
        us4 gvo0 = *(const us4*)(gb + (768 + u0) * 16);
        us4 gvo1 = *(const us4*)(gb + (768 + u1) * 16);

        // streamed weights (gates g,o), reloaded each step (L2-hot)
        short8 wg0[8], wg1[8], wo0[8], wo1[8];
#pragma unroll
        for (int kt = 0; kt < 8; ++kt) {
            wg0[kt] = *(const short8*)(pg0 + kt * 32);
            wg1[kt] = *(const short8*)(pg1 + kt * 32);
            wo0[kt] = *(const short8*)(po0 + kt * 32);
            wo1[kt] = *(const short8*)(po1 + kt * 32);
        }

        const char* hb = h_s[p];
        f32x4 acc0 = {0.f,0.f,0.f,0.f}, acc1 = {0.f,0.f,0.f,0.f};
        f32x4 acc2 = {0.f,0.f,0.f,0.f}, acc3 = {0.f,0.f,0.f,0.f};
        f32x4 acc4 = {0.f,0.f,0.f,0.f}, acc5 = {0.f,0.f,0.f,0.f};
        f32x4 acc6 = {0.f,0.f,0.f,0.f}, acc7 = {0.f,0.f,0.f,0.f};

        KT_BLOCK(0,   0,  1,  2,  3,  32, 33, 34, 35,  64, 65, 66, 67,  96, 97, 98, 99)
        KT_BLOCK(1,   4,  5,  6,  7,  36, 37, 38, 39,  68, 69, 70, 71, 100,101,102,103)
        KT_BLOCK(2,   8,  9, 10, 11,  40, 41, 42, 43,  72, 73, 74, 75, 104,105,106,107)
        KT_BLOCK(3,  12, 13, 14, 15,  44, 45, 46, 47,  76, 77, 78, 79, 108,109,110,111)
        KT_BLOCK(4,  16, 17, 18, 19,  48, 49, 50, 51,  80, 81, 82, 83, 112,113,114,115)
        KT_BLOCK(5,  20, 21, 22, 23,  52, 53, 54, 55,  84, 85, 86, 87, 116,117,118,119)
        KT_BLOCK(6,  24, 25, 26, 27,  56, 57, 58, 59,  88, 89, 90, 91, 120,121,122,123)
        KT_BLOCK(7,  28, 29, 30, 31,  60, 61, 62, 63,  92, 93, 94, 95, 124,125,126,127)

        asm volatile("s_nop 7\n\ts_nop 7");   // MFMA->VALU hazard

        // ---- pointwise (lane owns units u0,u1; rows lg*4+r) --------------
        char* hw = h_s[p ^ 1];
        ushortT hh0[4], hh1[4];
#pragma unroll
        for (int r = 0; r < 4; ++r) {
            float i_ = acc0[r] + bf2f(gvi0[r]);
            float f_ = acc2[r] + bf2f(gvf0[r]);
            float g_ = acc4[r] + bf2f(gvg0[r]);
            float o_ = acc6[r] + bf2f(gvo0[r]);
            float cn = fsig(f_) * c[0][r] + fsig(i_) * ftanh(g_);
            float hn = fsig(o_) * ftanh(cn);
            c[0][r] = cn;
            hh0[r] = f2bf(hn);
            int row = lg * 4 + r;
            *(ushortT*)&hw[(row * 512 + u0 * 2) ^ ((row & 7) << 4)] = hh0[r];
        }
#pragma unroll
        for (int r = 0; r < 4; ++r) {
            float i_ = acc1[r] + bf2f(gvi1[r]);
            float f_ = acc3[r] + bf2f(gvf1[r]);
            float g_ = acc5[r] + bf2f(gvg1[r]);
            float o_ = acc7[r] + bf2f(gvo1[r]);
            float cn = fsig(f_) * c[1][r] + fsig(i_) * ftanh(g_);
            float hn = fsig(o_) * ftanh(cn);
            c[1][r] = cn;
            hh1[r] = f2bf(hn);
            int row = lg * 4 + r;
            *(ushortT*)&hw[(row * 512 + u1 * 2) ^ ((row & 7) << 4)] = hh1[r];
        }

        // hout stores: async, NOT drained by the lgkm-only barrier
#pragma unroll
        for (int r = 0; r < 4; ++r) {
            if (t_glob < lenr[r]) {
                int row = lg * 4 + r;
                int tp = dir ? (lenr[r] - 1 - t_glob) : t_glob;
                size_t base = ((size_t)((g * 16 + row) * 512 + tp)) * 512 + dir * 256;
                hout[base + u0] = hh0[r];
                hout[base + u1] = hh1[r];
            }
        }

        BARRIER_LGKM();
        p ^= 1;
    }

    // ---- save state -------------------------------------------------------
    float* cs = st_c + ((size_t)dirg * 512 + tid) * 8;
#pragma unroll
    for (int s = 0; s < 2; ++s)
#pragma unroll
        for (int r = 0; r < 4; ++r) cs[s * 4 + r] = c[s][r];
    int* hs = (int*)st_h + dirg * 2048;
    for (int i = tid; i < 2048; i += 512) hs[i] = ((int*)h_s[p])[i];
}

// K-scores: scores[b,t,:] = h[b,t,:] (bf16) @ w_out^T + b_out  (t < len)
__global__ __launch_bounds__(256) void k_scores_bf(
    const int* __restrict__ lens, const ushortT* __restrict__ hout,
    const float* __restrict__ w_out, const float* __restrict__ b_out,
    float* __restrict__ scores)
{
    const int b = blockIdx.y;
    const int t0 = blockIdx.x * 32;
    const int len = lens[b];
    if (t0 >= len) return;

    __shared__ float w_s[20 * 513];
    __shared__ float row_s[512];
    __shared__ float part_s[20][9];
    __shared__ float bo_s[20];

    const int tid = threadIdx.x;
    for (int e = tid; e < 20 * 512; e += 256) w_s[(e >> 9) * 513 + (e & 511)] = w_out[e];
    if (tid < 20) bo_s[tid] = b_out[tid];
    __syncthreads();

    const int tend = min(t0 + 32, len);
    const int tag = tid >> 3, sl = tid & 7;
    for (int t = t0; t < tend; ++t) {
        const ushortT* hr = hout + ((size_t)(b * 512 + t)) * 512;
        unsigned int v = ((const unsigned int*)hr)[tid];
        row_s[tid * 2] = bf2f(v & 0xffffu);
        row_s[tid * 2 + 1] = bf2f(v >> 16);
        __syncthreads();
        if (tid < 160) {
            float s = 0.0f;
#pragma unroll 8
            for (int j = 0; j < 64; ++j) {
                int k = sl + (((j + tag) & 63) << 3);
                s = fmaf(w_s[tag * 513 + k], row_s[k], s);
            }
            part_s[tag][sl] = s;
        }
        __syncthreads();
        if (tid < 20) {
            float s = bo_s[tid];
#pragma unroll
            for (int j = 0; j < 8; ++j) s += part_s[tid][j];
            scores[((size_t)(b * 512 + t)) * 20 + tid] = s;
        }
        __syncthreads();
    }
}

__global__ __launch_bounds__(64) void k_viterbi_s(
    const int* __restrict__ lens, const float* __restrict__ scores,
    const float* __restrict__ trans, float* __restrict__ out)
{
    const int b = blockIdx.x;
    const int lane = threadIdx.x;
    const int len = lens[b];

    __shared__ float tr_s[20][21];
    __shared__ float fv_s[20];
    __shared__ float term_s[20];
    __shared__ unsigned char bp_s[512][20];
    __shared__ unsigned char path_s[512];

    for (int e = lane; e < 400; e += 64) tr_s[e / 20][e % 20] = trans[e];
    if (lane < 20) fv_s[lane] = (lane == TAG_START) ? 0.0f : NEGV;
    __syncthreads();

    const float* sc = scores + ((size_t)(b << 9)) * 20;
    for (int t = 0; t < len; ++t) {
        float m = 0.0f; int arg = 0;
        if (lane < 20) {
            m = fv_s[0] + tr_s[lane][0]; arg = 0;
#pragma unroll
            for (int k = 1; k < 20; ++k) {
                float v = fv_s[k] + tr_s[lane][k];
                if (v > m) { m = v; arg = k; }
            }
            m += sc[t * 20 + lane];
        }
        __syncthreads();
        if (lane < 20) { fv_s[lane] = m; bp_s[t][lane] = (unsigned char)arg; }
        __syncthreads();
    }

    if (lane < 20) term_s[lane] = fv_s[lane] + tr_s[TAG_STOP][lane];
    __syncthreads();

    if (lane == 0) {
        float m = term_s[0]; int arg = 0;
        for (int k = 1; k < 20; ++k) if (term_s[k] > m) { m = term_s[k]; arg = k; }
        out[b] = m;
        int cur = arg;
        path_s[len - 1] = (unsigned char)cur;
        for (int j = len - 1; j >= 1; --j) {
            cur = bp_s[j][cur];
            path_s[j - 1] = (unsigned char)cur;
        }
    }
    __syncthreads();

    float* po = out + NB + ((size_t)b << 9);
    for (int p = lane; p < NL; p += 64) po[p] = (p < len) ? (float)path_s[p] : 0.0f;
}

// ===========================================================================
// FALLBACK PATH (round-2 proven)
// ===========================================================================
__global__ __launch_bounds__(256) void k_transpose_fb(
    const float* __restrict__ whh_f, const float* __restrict__ whh_b,
    const float* __restrict__ wih_f, const float* __restrict__ wih_b,
    float* __restrict__ thh_f, float* __restrict__ thh_b,
    float* __restrict__ tih_f, float* __restrict__ tih_b)
{
    int e = blockIdx.x * 256 + threadIdx.x;
    const float* wm; float* wt;
    switch (blockIdx.y) {
        case 0: wm = whh_f; wt = thh_f; break;
        case 1: wm = whh_b; wt = thh_b; break;
        case 2: wm = wih_f; wt = tih_f; break;
        default: wm = wih_b; wt = tih_b; break;
    }
    int n = e >> 8, k = e & 255;
    wt[k * 1024 + n] = wm[e];
}

__global__ __launch_bounds__(1024) void k_rec_fb(
    const int* __restrict__ sent, const int* __restrict__ lens,
    const float* __restrict__ emb,
    const float* __restrict__ thh_f, const float* __restrict__ thh_b,
    const float* __restrict__ tih_f, const float* __restrict__ tih_b,
    const float* __restrict__ b_ih_f, const float* __restrict__ b_hh_f,
    const float* __restrict__ b_ih_b, const float* __restrict__ b_hh_b,
    const float* __restrict__ w_out,
    float* __restrict__ sc_f, float* __restrict__ sc_b)
{
    const int b = blockIdx.x, dir = blockIdx.y;
    const int len = lens[b];
    const int n = threadIdx.x;
    const float* Whh = dir ? thh_b : thh_f;
    const float* Wih = dir ? tih_b : tih_f;
    const float* bi = dir ? b_ih_b : b_ih_f;
    const float* bh = dir ? b_hh_b : b_hh_f;
    float* scout = dir ? sc_b : sc_f;

    __shared__ float x_s[256];
    __shared__ float h_s[256];
    __shared__ float g_s[1024];
    __shared__ float bias_s[1024];
    __shared__ float wout_s[20 * 257];
    __shared__ float part_s[20][8];

    bias_s[n] = bi[n] + bh[n];
    for (int e = n; e < 20 * 256; e += 1024)
        wout_s[(e >> 8) * 257 + (e & 255)] = w_out[(e >> 8) * 512 + dir * 256 + (e & 255)];
    if (n < 256) h_s[n] = 0.0f;
    float c = 0.0f;
    __syncthreads();

    const int sbase = b << 9;
    for (int t = 0; t < len; ++t) {
        if (n < 256) {
            int ti = dir ? (len - 1 - t) : t;
            int tok = sent[sbase + ti];
            x_s[n] = emb[(size_t)tok * NE + n];
        }
        __syncthreads();
        float acc = bias_s[n];
        const float* wi = Wih + n;
        const float* wh = Whh + n;
#pragma unroll 8
        for (int k = 0; k < 256; ++k) {
            acc = fmaf(wh[(size_t)(k << 10)], h_s[k], acc);
            acc = fmaf(wi[(size_t)(k << 10)], x_s[k], acc);
        }
        g_s[n] = acc;
        __syncthreads();
        if (n < 256) {
            float ig = g_s[n], fg = g_s[n + 256], gg = g_s[n + 512], og = g_s[n + 768];
            float cn = sigf_slow(fg) * c + sigf_slow(ig) * tanhf(gg);
            float hn = sigf_slow(og) * tanhf(cn);
            c = cn; h_s[n] = hn;
        }
        __syncthreads();
        if (n < 160) {
            const int tag = n >> 3, sl = n & 7;
            const float* wrow = wout_s + tag * 257;
            float s = 0.0f;
#pragma unroll 8
            for (int j = 0; j < 32; ++j) { int k = sl + (j << 3); s = fmaf(wrow[k], h_s[k], s); }
            part_s[tag][sl] = s;
        }
        __syncthreads();
        if (n < 20) {
            float s = part_s[n][0];
#pragma unroll
            for (int j = 1; j < 8; ++j) s += part_s[n][j];
            int tp = dir ? (len - 1 - t) : t;
            scout[(size_t)(sbase + tp) * 20 + n] = s;
        }
    }
}

__global__ __launch_bounds__(64) void k_viterbi_fb(
    const int* __restrict__ lens,
    const float* __restrict__ sc_f, const float* __restrict__ sc_b,
    const float* __restrict__ b_out, const float* __restrict__ trans,
    float* __restrict__ out)
{
    const int b = blockIdx.x;
    const int lane = threadIdx.x;
    const int len = lens[b];

    __shared__ float tr_s[20][21];
    __shared__ float fv_s[20];
    __shared__ float term_s[20];
    __shared__ float bo_s[20];
    __shared__ unsigned char bp_s[512][20];
    __shared__ unsigned char path_s[512];

    for (int e = lane; e < 400; e += 64) tr_s[e / 20][e % 20] = trans[e];
    if (lane < 20) { fv_s[lane] = (lane == TAG_START) ? 0.0f : NEGV; bo_s[lane] = b_out[lane]; }
    __syncthreads();

    const size_t sb = (size_t)(b << 9) * 20;
    for (int t = 0; t < len; ++t) {
        float m = 0.0f; int arg = 0;
        if (lane < 20) {
            m = fv_s[0] + tr_s[lane][0]; arg = 0;
#pragma unroll
            for (int k = 1; k < 20; ++k) {
                float v = fv_s[k] + tr_s[lane][k];
                if (v > m) { m = v; arg = k; }
            }
            m += sc_f[sb + t * 20 + lane] + sc_b[sb + t * 20 + lane] + bo_s[lane];
        }
        __syncthreads();
        if (lane < 20) { fv_s[lane] = m; bp_s[t][lane] = (unsigned char)arg; }
        __syncthreads();
    }
    if (lane < 20) term_s[lane] = fv_s[lane] + tr_s[TAG_STOP][lane];
    __syncthreads();
    if (lane == 0) {
        float m = term_s[0]; int arg = 0;
        for (int k = 1; k < 20; ++k) if (term_s[k] > m) { m = term_s[k]; arg = k; }
        out[b] = m;
        int cur = arg;
        path_s[len - 1] = (unsigned char)cur;
        for (int j = len - 1; j >= 1; --j) { cur = bp_s[j][cur]; path_s[j - 1] = (unsigned char)cur; }
    }
    __syncthreads();
    float* po = out + NB + ((size_t)b << 9);
    for (int p = lane; p < NL; p += 64) po[p] = (p < len) ? (float)path_s[p] : 0.0f;
}

// ===========================================================================
extern "C" void kernel_launch(void* const* d_in, const int* in_sizes, int n_in,
                              void* d_out, int out_size, void* d_ws, size_t ws_size,
                              hipStream_t stream)
{
    const int*   sent   = (const int*)d_in[0];
    const int*   lens   = (const int*)d_in[1];
    const float* emb    = (const float*)d_in[2];
    const float* w_ih_f = (const float*)d_in[3];
    const float* w_hh_f = (const float*)d_in[4];
    const float* b_ih_f = (const float*)d_in[5];
    const float* b_hh_f = (const float*)d_in[6];
    const float* w_ih_b = (const float*)d_in[7];
    const float* w_hh_b = (const float*)d_in[8];
    const float* b_ih_b = (const float*)d_in[9];
    const float* b_hh_b = (const float*)d_in[10];
    const float* w_out  = (const float*)d_in[11];
    const float* b_out  = (const float*)d_in[12];
    const float* trans  = (const float*)d_in[13];
    float* out = (float*)d_out;

    char* w = (char*)d_ws;
    // layout (gin now bf16: 8 dirg * CH * 16384 ushorts = CH * 256 KB):
    const size_t base = 38612992;
    int CH = 0;
    const int chs[6] = {512, 256, 192, 128, 64, 32};
    for (int i = 0; i < 6; ++i)
        if (base + (size_t)chs[i] * 262144 <= ws_size) { CH = chs[i]; break; }

    if (CH) {
        ushortT* whh16 = (ushortT*)(w);
        ushortT* wih16 = (ushortT*)(w + 1048576);
        float*   biasc = (float*)(w + 2097152);
        ushortT* st_h  = (ushortT*)(w + 2105344);
        float*   st_c  = (float*)(w + 2170880);
        float*   scores= (float*)(w + 2437120);
        ushortT* hout  = (ushortT*)(w + 5058560);
        ushortT* gin16 = (ushortT*)(w + base);

        k_cvtw<<<dim3(1024, 4), 256, 0, stream>>>(w_hh_f, w_hh_b, w_ih_f, w_ih_b, whh16, wih16);
        k_bias<<<2, 1024, 0, stream>>>(b_ih_f, b_hh_f, b_ih_b, b_hh_b, biasc);

        for (int cs = 0; cs < NL; cs += CH) {
            k_gin_mfma<<<dim3(4, CH / 16, 4), 512, 0, stream>>>(
                sent, lens, emb, wih16, biasc, gin16, cs, CH);
            k_rec_mfma<<<dim3(4, 2), 512, 0, stream>>>(
                lens, whh16, gin16, hout, st_h, st_c, cs, CH);
        }
        k_scores_bf<<<dim3(16, 64), 256, 0, stream>>>(lens, hout, w_out, b_out, scores);
        k_viterbi_s<<<64, 64, 0, stream>>>(lens, scores, trans, out);
    } else {
        float* ws2   = (float*)d_ws;
        float* thh_f = ws2;
        float* thh_b = thh_f + 262144;
        float* tih_f = thh_b + 262144;
        float* tih_b = tih_f + 262144;
        float* sc_f  = tih_b + 262144;
        float* sc_b  = sc_f + (size_t)NB * NL * NT;

        k_transpose_fb<<<dim3(1024, 4), 256, 0, stream>>>(
            w_hh_f, w_hh_b, w_ih_f, w_ih_b, thh_f, thh_b, tih_f, tih_b);
        k_rec_fb<<<dim3(NB, 2), 1024, 0, stream>>>(
            sent, lens, emb, thh_f, thh_b, tih_f, tih_b,
            b_ih_f, b_hh_f, b_ih_b, b_hh_b, w_out, sc_f, sc_b);
        k_viterbi_fb<<<NB, 64, 0, stream>>>(lens, sc_f, sc_b, b_out, trans, out);
    }
}

// Round 13
// 3982.039 us; speedup vs baseline: 1.3966x; 1.3966x over previous
//
#include <hip/hip_runtime.h>
#include <hip/hip_bf16.h>
#include <math.h>

#define NV 50000
#define NE 256
#define NH 256
#define NT 20
#define NB 64
#define NL 512
#define TAG_START 18
#define TAG_STOP 19
#define NEGV -10000.0f

typedef unsigned short ushortT;
typedef __attribute__((ext_vector_type(4))) float f32x4;
typedef __attribute__((ext_vector_type(8))) short short8;
typedef __attribute__((ext_vector_type(4))) unsigned short us4;

#define PINV(x) asm volatile("" : "+v"(x))

__device__ __forceinline__ float sigf_slow(float x) { return 1.0f / (1.0f + expf(-x)); }
__device__ __forceinline__ float fsig(float x) { return 1.0f / (1.0f + __expf(-x)); }
__device__ __forceinline__ float ftanh(float x) { return 1.0f - 2.0f / (1.0f + __expf(2.0f * x)); }
__device__ __forceinline__ ushortT f2bf(float f) {
    unsigned int u = __float_as_uint(f);
    u += 0x7fffu + ((u >> 16) & 1u);
    return (ushortT)(u >> 16);
}
__device__ __forceinline__ float bf2f(unsigned int bits16) {
    return __uint_as_float(bits16 << 16);
}

// ---- weight load into literal AGPRs ---------------------------------------
#define WRW(A0,A1,A2,A3,PTR) do {                                   \
    int4 _u = *(const int4*)(PTR);                                  \
    asm volatile("v_accvgpr_write_b32 a" #A0 ", %0\n\t"             \
                 "v_accvgpr_write_b32 a" #A1 ", %1\n\t"             \
                 "v_accvgpr_write_b32 a" #A2 ", %2\n\t"             \
                 "v_accvgpr_write_b32 a" #A3 ", %3"                 \
                 :: "v"(_u.x), "v"(_u.y), "v"(_u.z), "v"(_u.w)      \
                 : "a" #A0, "a" #A1, "a" #A2, "a" #A3);             \
} while (0)

// MFMA with B in literal AGPR range, acc in VGPRs (all-asm; round-11-proven)
#define MFMA_AG(ACC, AF, A0,A1,A2,A3)                                           \
    asm volatile("v_mfma_f32_16x16x32_bf16 %0, %1, a[" #A0 ":" #A3 "], %0"      \
                 : "+v"(ACC) : "v"(AF) : "a" #A0, "a" #A1, "a" #A2, "a" #A3)

// MFMA with B in VGPRs (LDS-loaded or streamed); all-asm (round-11-proven)
#define MFMA_SV(ACC, AF, BW)                                                    \
    asm volatile("v_mfma_f32_16x16x32_bf16 %0, %1, %2, %0"                      \
                 : "+v"(ACC) : "v"(AF), "v"(BW))

// one k-tile: A-frag from LDS, i/f from AGPR, g from LDS, o streamed — ALL asm
#define KT_BLOCK(KT, I0a,I0b,I0c,I0d, I1a,I1b,I1c,I1d, F0a,F0b,F0c,F0d, F1a,F1b,F1c,F1d, WO0, WO1) \
    {                                                                                     \
        int a_ = (lr * 512 + (KT) * 64 + lg * 16) ^ ((lr & 7) << 4);                      \
        short8 af = *(const short8*)&hb[a_];                                              \
        short8 wgA = *(const short8*)&wl_s[wlbase + 0 * 65536 + (KT) * 8192];             \
        short8 wgB = *(const short8*)&wl_s[wlbase + 1 * 65536 + (KT) * 8192];             \
        MFMA_AG(acc0, af, I0a,I0b,I0c,I0d);                                               \
        MFMA_AG(acc1, af, I1a,I1b,I1c,I1d);                                               \
        MFMA_AG(acc2, af, F0a,F0b,F0c,F0d);                                               \
        MFMA_AG(acc3, af, F1a,F1b,F1c,F1d);                                               \
        MFMA_SV(acc4, af, wgA);                                                           \
        MFMA_SV(acc5, af, wgB);                                                           \
        MFMA_SV(acc6, af, WO0);                                                           \
        MFMA_SV(acc7, af, WO1);                                                           \
    }

#define BARRIER_LGKM() asm volatile("s_waitcnt lgkmcnt(0)\n\ts_barrier" ::: "memory")

// ===========================================================================
// FAST PATH
// ===========================================================================

__global__ __launch_bounds__(256) void k_cvtw(
    const float* __restrict__ whh_f, const float* __restrict__ whh_b,
    const float* __restrict__ wih_f, const float* __restrict__ wih_b,
    ushortT* __restrict__ whh16, ushortT* __restrict__ wih16)
{
    int idx = blockIdx.x * 256 + threadIdx.x;     // < 262144
    const float* s; ushortT* d;
    switch (blockIdx.y) {
        case 0: s = whh_f; d = whh16;            break;
        case 1: s = whh_b; d = whh16 + 262144;   break;
        case 2: s = wih_f; d = wih16;            break;
        default: s = wih_b; d = wih16 + 262144;  break;
    }
    d[idx] = f2bf(s[idx]);
}

__global__ __launch_bounds__(1024) void k_bias(
    const float* __restrict__ bih_f, const float* __restrict__ bhh_f,
    const float* __restrict__ bih_b, const float* __restrict__ bhh_b,
    float* __restrict__ biasc)
{
    int n = threadIdx.x;
    if (blockIdx.x == 0) biasc[n] = bih_f[n] + bhh_f[n];
    else                 biasc[1024 + n] = bih_b[n] + bhh_b[n];
}

// K-gin: gin16[dirg][t][col*16 + row] = bf16(x_t @ Wih^T + bias)
__global__
__attribute__((amdgpu_flat_work_group_size(512, 512)))
__attribute__((amdgpu_waves_per_eu(2, 2)))
void k_gin_mfma(
    const int* __restrict__ sent, const int* __restrict__ lens,
    const float* __restrict__ emb, const ushortT* __restrict__ wih16,
    const float* __restrict__ biasc, ushortT* __restrict__ gin16,
    int chunk_start, int CH)
{
    const int g = blockIdx.x, tsub = blockIdx.y;
    const int dir = blockIdx.z >> 1, half = blockIdx.z & 1;
    const int gmax = lens[g * 16];
    const int tt0 = tsub * 16;
    if (chunk_start + tt0 >= gmax) return;

    const int tid = threadIdx.x;
    const int w = tid >> 6, l = tid & 63, lr = l & 15, lg = l >> 4;

    __shared__ char x_raw[16 * 512];

    const int ucol = half * 128 + w * 16 + lr;
    short8 bfr[4][8];
    float bias_l[4];
    const ushortT* wsrc = wih16 + dir * 262144;
#pragma unroll
    for (int nt = 0; nt < 4; ++nt) {
        int col = nt * 256 + ucol;
        bias_l[nt] = biasc[dir * 1024 + col];
#pragma unroll
        for (int kt = 0; kt < 8; ++kt)
            bfr[nt][kt] = *(const short8*)(wsrc + (size_t)col * 256 + kt * 32 + lg * 8);
    }
#pragma unroll
    for (int nt = 0; nt < 4; ++nt) {
        PINV(bias_l[nt]);
#pragma unroll
        for (int kt = 0; kt < 8; ++kt) PINV(bfr[nt][kt]);
    }

    const int srow = tid >> 5, sseg = tid & 31;
    const int slen = lens[g * 16 + srow];
    const int sb = (g * 16 + srow) * 512;

    for (int i = 0; i < 16; ++i) {
        int tg = chunk_start + tt0 + i;
        if (tg >= gmax) break;

        int tsrc = dir ? (slen - 1 - tg) : tg;
        if (tsrc < 0) tsrc = 0;
        if (tsrc > 511) tsrc = 511;
        int tok = sent[sb + tsrc];
        const float* es = emb + (size_t)tok * 256 + sseg * 8;
        float4 e0 = *(const float4*)es;
        float4 e1 = *(const float4*)(es + 4);
        short8 xv;
        xv[0] = (short)f2bf(e0.x); xv[1] = (short)f2bf(e0.y);
        xv[2] = (short)f2bf(e0.z); xv[3] = (short)f2bf(e0.w);
        xv[4] = (short)f2bf(e1.x); xv[5] = (short)f2bf(e1.y);
        xv[6] = (short)f2bf(e1.z); xv[7] = (short)f2bf(e1.w);
        int sa = (srow * 512 + sseg * 16) ^ ((srow & 7) << 4);
        *(short8*)&x_raw[sa] = xv;
        __syncthreads();

        short8 af[8];
#pragma unroll
        for (int kt = 0; kt < 8; ++kt) {
            int a = (lr * 512 + kt * 64 + lg * 16) ^ ((lr & 7) << 4);
            af[kt] = *(const short8*)&x_raw[a];
        }
        f32x4 acc[4];
#pragma unroll
        for (int nt = 0; nt < 4; ++nt) {
            acc[nt][0] = bias_l[nt]; acc[nt][1] = bias_l[nt];
            acc[nt][2] = bias_l[nt]; acc[nt][3] = bias_l[nt];
        }
#pragma unroll
        for (int kt = 0; kt < 8; ++kt)
#pragma unroll
            for (int nt = 0; nt < 4; ++nt)
                acc[nt] = __builtin_amdgcn_mfma_f32_16x16x32_bf16(af[kt], bfr[nt][kt], acc[nt], 0, 0, 0);

        ushortT* gp = gin16 + ((size_t)((dir * 4 + g) * CH + (tt0 + i))) * 16384;
#pragma unroll
        for (int nt = 0; nt < 4; ++nt) {
            int col = nt * 256 + ucol;
            us4 st;
            st[0] = f2bf(acc[nt][0]); st[1] = f2bf(acc[nt][1]);
            st[2] = f2bf(acc[nt][2]); st[3] = f2bf(acc[nt][3]);
            *(us4*)(gp + col * 16 + lg * 4) = st;
        }
        __syncthreads();
    }
}

// K-rec v6: ONE WG (512 thr) per (group,dir). No cross-CU exchange.
//   Gates i,f in AGPR a0-a127; gate g in LDS (conflict-free frag-major);
//   gate o streamed 2-deep. ALL MFMAs inline asm (no builtins in this
//   kernel -> compiler never touches AGPRs).
__global__
__attribute__((amdgpu_flat_work_group_size(512, 512)))
__attribute__((amdgpu_waves_per_eu(2, 2)))
void k_rec_mfma(
    const int* __restrict__ lens, const ushortT* __restrict__ whh16,
    const ushortT* __restrict__ gin16, ushortT* __restrict__ hout,
    ushortT* __restrict__ st_h, float* __restrict__ st_c,
    int chunk_start, int CH)
{
    const int g = blockIdx.x, dir = blockIdx.y;
    const int gmax = lens[g * 16];
    const int nsteps = min(CH, gmax - chunk_start);
    if (nsteps <= 0) return;

    const int tid = threadIdx.x;
    const int w = tid >> 6, l = tid & 63, lr = l & 15, lg = l >> 4;
    const int dirg = dir * 4 + g;

    __shared__ char h_s[2][8192];     // h, double-buffered, XOR-swizzled
    __shared__ char wl_s[131072];     // gate-g weights, frag-major (conflict-free)

    int lenr[4];
#pragma unroll
    for (int r = 0; r < 4; ++r) lenr[r] = lens[g * 16 + lg * 4 + r];

    const ushortT* wsrc = whh16 + dir * 262144;
    const int u0 = w * 32 + lr, u1 = w * 32 + 16 + lr;

    // ---- AGPR weights: gates i,f for units u0,u1 --------------------------
    {
        const ushortT* qi0 = wsrc + (size_t)(0   + u0) * 256 + lg * 8;
        const ushortT* qi1 = wsrc + (size_t)(0   + u1) * 256 + lg * 8;
        const ushortT* qf0 = wsrc + (size_t)(256 + u0) * 256 + lg * 8;
        const ushortT* qf1 = wsrc + (size_t)(256 + u1) * 256 + lg * 8;
        WRW(  0,  1,  2,  3, qi0 +   0); WRW(  4,  5,  6,  7, qi0 +  32);
        WRW(  8,  9, 10, 11, qi0 +  64); WRW( 12, 13, 14, 15, qi0 +  96);
        WRW( 16, 17, 18, 19, qi0 + 128); WRW( 20, 21, 22, 23, qi0 + 160);
        WRW( 24, 25, 26, 27, qi0 + 192); WRW( 28, 29, 30, 31, qi0 + 224);
        WRW( 32, 33, 34, 35, qi1 +   0); WRW( 36, 37, 38, 39, qi1 +  32);
        WRW( 40, 41, 42, 43, qi1 +  64); WRW( 44, 45, 46, 47, qi1 +  96);
        WRW( 48, 49, 50, 51, qi1 + 128); WRW( 52, 53, 54, 55, qi1 + 160);
        WRW( 56, 57, 58, 59, qi1 + 192); WRW( 60, 61, 62, 63, qi1 + 224);
        WRW( 64, 65, 66, 67, qf0 +   0); WRW( 68, 69, 70, 71, qf0 +  32);
        WRW( 72, 73, 74, 75, qf0 +  64); WRW( 76, 77, 78, 79, qf0 +  96);
        WRW( 80, 81, 82, 83, qf0 + 128); WRW( 84, 85, 86, 87, qf0 + 160);
        WRW( 88, 89, 90, 91, qf0 + 192); WRW( 92, 93, 94, 95, qf0 + 224);
        WRW( 96, 97, 98, 99, qf1 +   0); WRW(100,101,102,103, qf1 +  32);
        WRW(104,105,106,107, qf1 +  64); WRW(108,109,110,111, qf1 +  96);
        WRW(112,113,114,115, qf1 + 128); WRW(116,117,118,119, qf1 + 160);
        WRW(120,121,122,123, qf1 + 192); WRW(124,125,126,127, qf1 + 224);
        asm volatile("s_nop 1");
    }

    // ---- LDS gate-g weights, frag-major: chunk(t2,kt,w,lg,lr) -------------
    //   byte off = id*16, id = ((t2*8+kt)*8 + w)*64 + (lg*16+lr); a wave
    //   reads 64 consecutive 16B chunks per (t2,kt) -> conflict-free.
    for (int i = 0; i < 16; ++i) {
        int id = i * 512 + tid;                 // 8192 chunks
        int t2 = id >> 12;
        int kt = (id >> 9) & 7;
        int w_ = (id >> 6) & 7;
        int l6 = id & 63;
        int lg_ = l6 >> 4, lr_ = l6 & 15;
        int col = 512 + w_ * 32 + t2 * 16 + lr_;
        *(int4*)&wl_s[id * 16] = *(const int4*)(wsrc + (size_t)col * 256 + kt * 32 + lg_ * 8);
    }

    // ---- state init / restore --------------------------------------------
    float c[2][4];
    if (chunk_start == 0) {
#pragma unroll
        for (int s = 0; s < 2; ++s)
#pragma unroll
            for (int r = 0; r < 4; ++r) c[s][r] = 0.0f;
        for (int i = tid; i < 2048; i += 512) ((int*)h_s[0])[i] = 0;
    } else {
        const float* cs = st_c + ((size_t)dirg * 512 + tid) * 8;
#pragma unroll
        for (int s = 0; s < 2; ++s)
#pragma unroll
            for (int r = 0; r < 4; ++r) c[s][r] = cs[s * 4 + r];
        const int* hs = (const int*)st_h + dirg * 2048;
        for (int i = tid; i < 2048; i += 512) ((int*)h_s[0])[i] = hs[i];
    }
    __syncthreads();

    // streamed gate-o base pointers + per-lane constants
    const ushortT* po0 = wsrc + (size_t)(768 + u0) * 256 + lg * 8;
    const ushortT* po1 = wsrc + (size_t)(768 + u1) * 256 + lg * 8;
    const int wlbase = w * 1024 + (lg * 16 + lr) * 16;
    const ushortT* ginp = gin16 + (size_t)dirg * CH * 16384;

    // prologue: o-frags for kt=0
    short8 woA0 = *(const short8*)(po0 + 0);
    short8 woA1 = *(const short8*)(po1 + 0);

    int p = 0;
    for (int tt = 0; tt < nsteps; ++tt) {
        const int t_glob = chunk_start + tt;

        // gin (bf16): consumed in pointwise
        const ushortT* gb = ginp + (size_t)tt * 16384 + lg * 4;
        us4 gvi0 = *(const us4*)(gb + (0   + u0) * 16);
        us4 gvi1 = *(const us4*)(gb + (0   + u1) * 16);
        us4 gvf0 = *(const us4*)(gb + (256 + u0) * 16);
        us4 gvf1 = *(const us4*)(gb + (256 + u1) * 16);
        us4 gvg0 = *(const us4*)(gb + (512 + u0) * 16);
        us4 gvg1 = *(const us4*)(gb + (512 + u1) * 16);
        us4 gvo0 = *(const us4*)(gb + (768 + u0) * 16);
        us4 gvo1 = *(const us4*)(gb + (768 + u1) * 16);

        const char* hb = h_s[p];
        f32x4 acc0 = {0.f,0.f,0.f,0.f}, acc1 = {0.f,0.f,0.f,0.f};
        f32x4 acc2 = {0.f,0.f,0.f,0.f}, acc3 = {0.f,0.f,0.f,0.f};
        f32x4 acc4 = {0.f,0.f,0.f,0.f}, acc5 = {0.f,0.f,0.f,0.f};
        f32x4 acc6 = {0.f,0.f,0.f,0.f}, acc7 = {0.f,0.f,0.f,0.f};
        short8 woB0, woB1;

        woB0 = *(const short8*)(po0 + 1 * 32); woB1 = *(const short8*)(po1 + 1 * 32);
        KT_BLOCK(0,   0,  1,  2,  3,  32, 33, 34, 35,  64, 65, 66, 67,  96, 97, 98, 99, woA0, woA1)
        woA0 = *(const short8*)(po0 + 2 * 32); woA1 = *(const short8*)(po1 + 2 * 32);
        KT_BLOCK(1,   4,  5,  6,  7,  36, 37, 38, 39,  68, 69, 70, 71, 100,101,102,103, woB0, woB1)
        woB0 = *(const short8*)(po0 + 3 * 32); woB1 = *(const short8*)(po1 + 3 * 32);
        KT_BLOCK(2,   8,  9, 10, 11,  40, 41, 42, 43,  72, 73, 74, 75, 104,105,106,107, woA0, woA1)
        woA0 = *(const short8*)(po0 + 4 * 32); woA1 = *(const short8*)(po1 + 4 * 32);
        KT_BLOCK(3,  12, 13, 14, 15,  44, 45, 46, 47,  76, 77, 78, 79, 108,109,110,111, woB0, woB1)
        woB0 = *(const short8*)(po0 + 5 * 32); woB1 = *(const short8*)(po1 + 5 * 32);
        KT_BLOCK(4,  16, 17, 18, 19,  48, 49, 50, 51,  80, 81, 82, 83, 112,113,114,115, woA0, woA1)
        woA0 = *(const short8*)(po0 + 6 * 32); woA1 = *(const short8*)(po1 + 6 * 32);
        KT_BLOCK(5,  20, 21, 22, 23,  52, 53, 54, 55,  84, 85, 86, 87, 116,117,118,119, woB0, woB1)
        woB0 = *(const short8*)(po0 + 7 * 32); woB1 = *(const short8*)(po1 + 7 * 32);
        KT_BLOCK(6,  24, 25, 26, 27,  56, 57, 58, 59,  88, 89, 90, 91, 120,121,122,123, woA0, woA1)
        woA0 = *(const short8*)(po0 + 0);      woA1 = *(const short8*)(po1 + 0);   // next step kt0
        KT_BLOCK(7,  28, 29, 30, 31,  60, 61, 62, 63,  92, 93, 94, 95, 124,125,126,127, woB0, woB1)

        asm volatile("s_nop 7\n\ts_nop 7");   // MFMA(asm) -> VALU read hazard

        // ---- pointwise (lane owns units u0,u1; rows lg*4+r) --------------
        char* hw = h_s[p ^ 1];
        ushortT hh0[4], hh1[4];
#pragma unroll
        for (int r = 0; r < 4; ++r) {
            float i_ = acc0[r] + bf2f(gvi0[r]);
            float f_ = acc2[r] + bf2f(gvf0[r]);
            float g_ = acc4[r] + bf2f(gvg0[r]);
            float o_ = acc6[r] + bf2f(gvo0[r]);
            float cn = fsig(f_) * c[0][r] + fsig(i_) * ftanh(g_);
            float hn = fsig(o_) * ftanh(cn);
            c[0][r] = cn;
            hh0[r] = f2bf(hn);
            int row = lg * 4 + r;
            *(ushortT*)&hw[(row * 512 + u0 * 2) ^ ((row & 7) << 4)] = hh0[r];
        }
#pragma unroll
        for (int r = 0; r < 4; ++r) {
            float i_ = acc1[r] + bf2f(gvi1[r]);
            float f_ = acc3[r] + bf2f(gvf1[r]);
            float g_ = acc5[r] + bf2f(gvg1[r]);
            float o_ = acc7[r] + bf2f(gvo1[r]);
            float cn = fsig(f_) * c[1][r] + fsig(i_) * ftanh(g_);
            float hn = fsig(o_) * ftanh(cn);
            c[1][r] = cn;
            hh1[r] = f2bf(hn);
            int row = lg * 4 + r;
            *(ushortT*)&hw[(row * 512 + u1 * 2) ^ ((row & 7) << 4)] = hh1[r];
        }

        // hout stores: async, not drained by the lgkm-only barrier
#pragma unroll
        for (int r = 0; r < 4; ++r) {
            if (t_glob < lenr[r]) {
                int row = lg * 4 + r;
                int tp = dir ? (lenr[r] - 1 - t_glob) : t_glob;
                size_t base = ((size_t)((g * 16 + row) * 512 + tp)) * 512 + dir * 256;
                hout[base + u0] = hh0[r];
                hout[base + u1] = hh1[r];
            }
        }

        BARRIER_LGKM();
        p ^= 1;
    }

    // ---- save state -------------------------------------------------------
    float* cs = st_c + ((size_t)dirg * 512 + tid) * 8;
#pragma unroll
    for (int s = 0; s < 2; ++s)
#pragma unroll
        for (int r = 0; r < 4; ++r) cs[s * 4 + r] = c[s][r];
    int* hs = (int*)st_h + dirg * 2048;
    for (int i = tid; i < 2048; i += 512) hs[i] = ((int*)h_s[p])[i];
}

// K-scores: scores[b,t,:] = h[b,t,:] (bf16) @ w_out^T + b_out  (t < len)
__global__ __launch_bounds__(256) void k_scores_bf(
    const int* __restrict__ lens, const ushortT* __restrict__ hout,
    const float* __restrict__ w_out, const float* __restrict__ b_out,
    float* __restrict__ scores)
{
    const int b = blockIdx.y;
    const int t0 = blockIdx.x * 32;
    const int len = lens[b];
    if (t0 >= len) return;

    __shared__ float w_s[20 * 513];
    __shared__ float row_s[512];
    __shared__ float part_s[20][9];
    __shared__ float bo_s[20];

    const int tid = threadIdx.x;
    for (int e = tid; e < 20 * 512; e += 256) w_s[(e >> 9) * 513 + (e & 511)] = w_out[e];
    if (tid < 20) bo_s[tid] = b_out[tid];
    __syncthreads();

    const int tend = min(t0 + 32, len);
    const int tag = tid >> 3, sl = tid & 7;
    for (int t = t0; t < tend; ++t) {
        const ushortT* hr = hout + ((size_t)(b * 512 + t)) * 512;
        unsigned int v = ((const unsigned int*)hr)[tid];
        row_s[tid * 2] = bf2f(v & 0xffffu);
        row_s[tid * 2 + 1] = bf2f(v >> 16);
        __syncthreads();
        if (tid < 160) {
            float s = 0.0f;
#pragma unroll 8
            for (int j = 0; j < 64; ++j) {
                int k = sl + (((j + tag) & 63) << 3);
                s = fmaf(w_s[tag * 513 + k], row_s[k], s);
            }
            part_s[tag][sl] = s;
        }
        __syncthreads();
        if (tid < 20) {
            float s = bo_s[tid];
#pragma unroll
            for (int j = 0; j < 8; ++j) s += part_s[tid][j];
            scores[((size_t)(b * 512 + t)) * 20 + tid] = s;
        }
        __syncthreads();
    }
}

__global__ __launch_bounds__(64) void k_viterbi_s(
    const int* __restrict__ lens, const float* __restrict__ scores,
    const float* __restrict__ trans, float* __restrict__ out)
{
    const int b = blockIdx.x;
    const int lane = threadIdx.x;
    const int len = lens[b];

    __shared__ float tr_s[20][21];
    __shared__ float fv_s[20];
    __shared__ float term_s[20];
    __shared__ unsigned char bp_s[512][20];
    __shared__ unsigned char path_s[512];

    for (int e = lane; e < 400; e += 64) tr_s[e / 20][e % 20] = trans[e];
    if (lane < 20) fv_s[lane] = (lane == TAG_START) ? 0.0f : NEGV;
    __syncthreads();

    const float* sc = scores + ((size_t)(b << 9)) * 20;
    for (int t = 0; t < len; ++t) {
        float m = 0.0f; int arg = 0;
        if (lane < 20) {
            m = fv_s[0] + tr_s[lane][0]; arg = 0;
#pragma unroll
            for (int k = 1; k < 20; ++k) {
                float v = fv_s[k] + tr_s[lane][k];
                if (v > m) { m = v; arg = k; }
            }
            m += sc[t * 20 + lane];
        }
        __syncthreads();
        if (lane < 20) { fv_s[lane] = m; bp_s[t][lane] = (unsigned char)arg; }
        __syncthreads();
    }

    if (lane < 20) term_s[lane] = fv_s[lane] + tr_s[TAG_STOP][lane];
    __syncthreads();

    if (lane == 0) {
        float m = term_s[0]; int arg = 0;
        for (int k = 1; k < 20; ++k) if (term_s[k] > m) { m = term_s[k]; arg = k; }
        out[b] = m;
        int cur = arg;
        path_s[len - 1] = (unsigned char)cur;
        for (int j = len - 1; j >= 1; --j) {
            cur = bp_s[j][cur];
            path_s[j - 1] = (unsigned char)cur;
        }
    }
    __syncthreads();

    float* po = out + NB + ((size_t)b << 9);
    for (int p = lane; p < NL; p += 64) po[p] = (p < len) ? (float)path_s[p] : 0.0f;
}

// ===========================================================================
// FALLBACK PATH (round-2 proven)
// ===========================================================================
__global__ __launch_bounds__(256) void k_transpose_fb(
    const float* __restrict__ whh_f, const float* __restrict__ whh_b,
    const float* __restrict__ wih_f, const float* __restrict__ wih_b,
    float* __restrict__ thh_f, float* __restrict__ thh_b,
    float* __restrict__ tih_f, float* __restrict__ tih_b)
{
    int e = blockIdx.x * 256 + threadIdx.x;
    const float* wm; float* wt;
    switch (blockIdx.y) {
        case 0: wm = whh_f; wt = thh_f; break;
        case 1: wm = whh_b; wt = thh_b; break;
        case 2: wm = wih_f; wt = tih_f; break;
        default: wm = wih_b; wt = tih_b; break;
    }
    int n = e >> 8, k = e & 255;
    wt[k * 1024 + n] = wm[e];
}

__global__ __launch_bounds__(1024) void k_rec_fb(
    const int* __restrict__ sent, const int* __restrict__ lens,
    const float* __restrict__ emb,
    const float* __restrict__ thh_f, const float* __restrict__ thh_b,
    const float* __restrict__ tih_f, const float* __restrict__ tih_b,
    const float* __restrict__ b_ih_f, const float* __restrict__ b_hh_f,
    const float* __restrict__ b_ih_b, const float* __restrict__ b_hh_b,
    const float* __restrict__ w_out,
    float* __restrict__ sc_f, float* __restrict__ sc_b)
{
    const int b = blockIdx.x, dir = blockIdx.y;
    const int len = lens[b];
    const int n = threadIdx.x;
    const float* Whh = dir ? thh_b : thh_f;
    const float* Wih = dir ? tih_b : tih_f;
    const float* bi = dir ? b_ih_b : b_ih_f;
    const float* bh = dir ? b_hh_b : b_hh_f;
    float* scout = dir ? sc_b : sc_f;

    __shared__ float x_s[256];
    __shared__ float h_s[256];
    __shared__ float g_s[1024];
    __shared__ float bias_s[1024];
    __shared__ float wout_s[20 * 257];
    __shared__ float part_s[20][8];

    bias_s[n] = bi[n] + bh[n];
    for (int e = n; e < 20 * 256; e += 1024)
        wout_s[(e >> 8) * 257 + (e & 255)] = w_out[(e >> 8) * 512 + dir * 256 + (e & 255)];
    if (n < 256) h_s[n] = 0.0f;
    float c = 0.0f;
    __syncthreads();

    const int sbase = b << 9;
    for (int t = 0; t < len; ++t) {
        if (n < 256) {
            int ti = dir ? (len - 1 - t) : t;
            int tok = sent[sbase + ti];
            x_s[n] = emb[(size_t)tok * NE + n];
        }
        __syncthreads();
        float acc = bias_s[n];
        const float* wi = Wih + n;
        const float* wh = Whh + n;
#pragma unroll 8
        for (int k = 0; k < 256; ++k) {
            acc = fmaf(wh[(size_t)(k << 10)], h_s[k], acc);
            acc = fmaf(wi[(size_t)(k << 10)], x_s[k], acc);
        }
        g_s[n] = acc;
        __syncthreads();
        if (n < 256) {
            float ig = g_s[n], fg = g_s[n + 256], gg = g_s[n + 512], og = g_s[n + 768];
            float cn = sigf_slow(fg) * c + sigf_slow(ig) * tanhf(gg);
            float hn = sigf_slow(og) * tanhf(cn);
            c = cn; h_s[n] = hn;
        }
        __syncthreads();
        if (n < 160) {
            const int tag = n >> 3, sl = n & 7;
            const float* wrow = wout_s + tag * 257;
            float s = 0.0f;
#pragma unroll 8
            for (int j = 0; j < 32; ++j) { int k = sl + (j << 3); s = fmaf(wrow[k], h_s[k], s); }
            part_s[tag][sl] = s;
        }
        __syncthreads();
        if (n < 20) {
            float s = part_s[n][0];
#pragma unroll
            for (int j = 1; j < 8; ++j) s += part_s[n][j];
            int tp = dir ? (len - 1 - t) : t;
            scout[(size_t)(sbase + tp) * 20 + n] = s;
        }
    }
}

__global__ __launch_bounds__(64) void k_viterbi_fb(
    const int* __restrict__ lens,
    const float* __restrict__ sc_f, const float* __restrict__ sc_b,
    const float* __restrict__ b_out, const float* __restrict__ trans,
    float* __restrict__ out)
{
    const int b = blockIdx.x;
    const int lane = threadIdx.x;
    const int len = lens[b];

    __shared__ float tr_s[20][21];
    __shared__ float fv_s[20];
    __shared__ float term_s[20];
    __shared__ float bo_s[20];
    __shared__ unsigned char bp_s[512][20];
    __shared__ unsigned char path_s[512];

    for (int e = lane; e < 400; e += 64) tr_s[e / 20][e % 20] = trans[e];
    if (lane < 20) { fv_s[lane] = (lane == TAG_START) ? 0.0f : NEGV; bo_s[lane] = b_out[lane]; }
    __syncthreads();

    const size_t sb = (size_t)(b << 9) * 20;
    for (int t = 0; t < len; ++t) {
        float m = 0.0f; int arg = 0;
        if (lane < 20) {
            m = fv_s[0] + tr_s[lane][0]; arg = 0;
#pragma unroll
            for (int k = 1; k < 20; ++k) {
                float v = fv_s[k] + tr_s[lane][k];
                if (v > m) { m = v; arg = k; }
            }
            m += sc_f[sb + t * 20 + lane] + sc_b[sb + t * 20 + lane] + bo_s[lane];
        }
        __syncthreads();
        if (lane < 20) { fv_s[lane] = m; bp_s[t][lane] = (unsigned char)arg; }
        __syncthreads();
    }
    if (lane < 20) term_s[lane] = fv_s[lane] + tr_s[TAG_STOP][lane];
    __syncthreads();
    if (lane == 0) {
        float m = term_s[0]; int arg = 0;
        for (int k = 1; k < 20; ++k) if (term_s[k] > m) { m = term_s[k]; arg = k; }
        out[b] = m;
        int cur = arg;
        path_s[len - 1] = (unsigned char)cur;
        for (int j = len - 1; j >= 1; --j) { cur = bp_s[j][cur]; path_s[j - 1] = (unsigned char)cur; }
    }
    __syncthreads();
    float* po = out + NB + ((size_t)b << 9);
    for (int p = lane; p < NL; p += 64) po[p] = (p < len) ? (float)path_s[p] : 0.0f;
}

// ===========================================================================
extern "C" void kernel_launch(void* const* d_in, const int* in_sizes, int n_in,
                              void* d_out, int out_size, void* d_ws, size_t ws_size,
                              hipStream_t stream)
{
    const int*   sent   = (const int*)d_in[0];
    const int*   lens   = (const int*)d_in[1];
    const float* emb    = (const float*)d_in[2];
    const float* w_ih_f = (const float*)d_in[3];
    const float* w_hh_f = (const float*)d_in[4];
    const float* b_ih_f = (const float*)d_in[5];
    const float* b_hh_f = (const float*)d_in[6];
    const float* w_ih_b = (const float*)d_in[7];
    const float* w_hh_b = (const float*)d_in[8];
    const float* b_ih_b = (const float*)d_in[9];
    const float* b_hh_b = (const float*)d_in[10];
    const float* w_out  = (const float*)d_in[11];
    const float* b_out  = (const float*)d_in[12];
    const float* trans  = (const float*)d_in[13];
    float* out = (float*)d_out;

    char* w = (char*)d_ws;
    // layout (gin bf16: 8 dirg * CH * 16384 ushorts = CH * 256 KB):
    const size_t base = 38612992;
    int CH = 0;
    const int chs[6] = {512, 256, 192, 128, 64, 32};
    for (int i = 0; i < 6; ++i)
        if (base + (size_t)chs[i] * 262144 <= ws_size) { CH = chs[i]; break; }

    if (CH) {
        ushortT* whh16 = (ushortT*)(w);
        ushortT* wih16 = (ushortT*)(w + 1048576);
        float*   biasc = (float*)(w + 2097152);
        ushortT* st_h  = (ushortT*)(w + 2105344);
        float*   st_c  = (float*)(w + 2170880);
        float*   scores= (float*)(w + 2437120);
        ushortT* hout  = (ushortT*)(w + 5058560);
        ushortT* gin16 = (ushortT*)(w + base);

        k_cvtw<<<dim3(1024, 4), 256, 0, stream>>>(w_hh_f, w_hh_b, w_ih_f, w_ih_b, whh16, wih16);
        k_bias<<<2, 1024, 0, stream>>>(b_ih_f, b_hh_f, b_ih_b, b_hh_b, biasc);

        for (int cs = 0; cs < NL; cs += CH) {
            k_gin_mfma<<<dim3(4, CH / 16, 4), 512, 0, stream>>>(
                sent, lens, emb, wih16, biasc, gin16, cs, CH);
            k_rec_mfma<<<dim3(4, 2), 512, 0, stream>>>(
                lens, whh16, gin16, hout, st_h, st_c, cs, CH);
        }
        k_scores_bf<<<dim3(16, 64), 256, 0, stream>>>(lens, hout, w_out, b_out, scores);
        k_viterbi_s<<<64, 64, 0, stream>>>(lens, scores, trans, out);
    } else {
        float* ws2   = (float*)d_ws;
        float* thh_f = ws2;
        float* thh_b = thh_f + 262144;
        float* tih_f = thh_b + 262144;
        float* tih_b = tih_f + 262144;
        float* sc_f  = tih_b + 262144;
        float* sc_b  = sc_f + (size_t)NB * NL * NT;

        k_transpose_fb<<<dim3(1024, 4), 256, 0, stream>>>(
            w_hh_f, w_hh_b, w_ih_f, w_ih_b, thh_f, thh_b, tih_f, tih_b);
        k_rec_fb<<<dim3(NB, 2), 1024, 0, stream>>>(
            sent, lens, emb, thh_f, thh_b, tih_f, tih_b,
            b_ih_f, b_hh_f, b_ih_b, b_hh_b, w_out, sc_f, sc_b);
        k_viterbi_fb<<<NB, 64, 0, stream>>>(lens, sc_f, sc_b, b_out, trans, out);
    }
}

// Round 14
// 2127.441 us; speedup vs baseline: 2.6141x; 1.8718x over previous
//
#include <hip/hip_runtime.h>
#include <hip/hip_bf16.h>
#include <math.h>

#define NV 50000
#define NE 256
#define NH 256
#define NT 20
#define NB 64
#define NL 512
#define TAG_START 18
#define TAG_STOP 19
#define NEGV -10000.0f

typedef unsigned short ushortT;
typedef __attribute__((ext_vector_type(4))) float f32x4;
typedef __attribute__((ext_vector_type(8))) short short8;
typedef __attribute__((ext_vector_type(4))) unsigned short us4;

#define PINV(x) asm volatile("" : "+v"(x))

__device__ __forceinline__ float sigf_slow(float x) { return 1.0f / (1.0f + expf(-x)); }
__device__ __forceinline__ float fsig(float x) { return 1.0f / (1.0f + __expf(-x)); }
__device__ __forceinline__ float ftanh(float x) { return 1.0f - 2.0f / (1.0f + __expf(2.0f * x)); }
__device__ __forceinline__ ushortT f2bf(float f) {
    unsigned int u = __float_as_uint(f);
    u += 0x7fffu + ((u >> 16) & 1u);
    return (ushortT)(u >> 16);
}
__device__ __forceinline__ float bf2f(unsigned int bits16) {
    return __uint_as_float(bits16 << 16);
}

// ===========================================================================
// FAST PATH
// ===========================================================================

__global__ __launch_bounds__(256) void k_cvtw(
    const float* __restrict__ whh_f, const float* __restrict__ whh_b,
    const float* __restrict__ wih_f, const float* __restrict__ wih_b,
    ushortT* __restrict__ whh16, ushortT* __restrict__ wih16)
{
    int idx = blockIdx.x * 256 + threadIdx.x;     // < 262144
    const float* s; ushortT* d;
    switch (blockIdx.y) {
        case 0: s = whh_f; d = whh16;            break;
        case 1: s = whh_b; d = whh16 + 262144;   break;
        case 2: s = wih_f; d = wih16;            break;
        default: s = wih_b; d = wih16 + 262144;  break;
    }
    d[idx] = f2bf(s[idx]);
}

__global__ __launch_bounds__(1024) void k_bias(
    const float* __restrict__ bih_f, const float* __restrict__ bhh_f,
    const float* __restrict__ bih_b, const float* __restrict__ bhh_b,
    float* __restrict__ biasc)
{
    int n = threadIdx.x;
    if (blockIdx.x == 0) biasc[n] = bih_f[n] + bhh_f[n];
    else                 biasc[1024 + n] = bih_b[n] + bhh_b[n];
}

// K-gin: gin16[dirg][t][col*16 + row] = bf16(x_t @ Wih^T + bias)
//   (round-13-proven, absmax 0.0)
__global__
__attribute__((amdgpu_flat_work_group_size(512, 512)))
__attribute__((amdgpu_waves_per_eu(2, 2)))
void k_gin_mfma(
    const int* __restrict__ sent, const int* __restrict__ lens,
    const float* __restrict__ emb, const ushortT* __restrict__ wih16,
    const float* __restrict__ biasc, ushortT* __restrict__ gin16,
    int chunk_start, int CH)
{
    const int g = blockIdx.x, tsub = blockIdx.y;
    const int dir = blockIdx.z >> 1, half = blockIdx.z & 1;
    const int gmax = lens[g * 16];
    const int tt0 = tsub * 16;
    if (chunk_start + tt0 >= gmax) return;

    const int tid = threadIdx.x;
    const int w = tid >> 6, l = tid & 63, lr = l & 15, lg = l >> 4;

    __shared__ char x_raw[16 * 512];

    const int ucol = half * 128 + w * 16 + lr;
    short8 bfr[4][8];
    float bias_l[4];
    const ushortT* wsrc = wih16 + dir * 262144;
#pragma unroll
    for (int nt = 0; nt < 4; ++nt) {
        int col = nt * 256 + ucol;
        bias_l[nt] = biasc[dir * 1024 + col];
#pragma unroll
        for (int kt = 0; kt < 8; ++kt)
            bfr[nt][kt] = *(const short8*)(wsrc + (size_t)col * 256 + kt * 32 + lg * 8);
    }
#pragma unroll
    for (int nt = 0; nt < 4; ++nt) {
        PINV(bias_l[nt]);
#pragma unroll
        for (int kt = 0; kt < 8; ++kt) PINV(bfr[nt][kt]);
    }

    const int srow = tid >> 5, sseg = tid & 31;
    const int slen = lens[g * 16 + srow];
    const int sb = (g * 16 + srow) * 512;

    for (int i = 0; i < 16; ++i) {
        int tg = chunk_start + tt0 + i;
        if (tg >= gmax) break;

        int tsrc = dir ? (slen - 1 - tg) : tg;
        if (tsrc < 0) tsrc = 0;
        if (tsrc > 511) tsrc = 511;
        int tok = sent[sb + tsrc];
        const float* es = emb + (size_t)tok * 256 + sseg * 8;
        float4 e0 = *(const float4*)es;
        float4 e1 = *(const float4*)(es + 4);
        short8 xv;
        xv[0] = (short)f2bf(e0.x); xv[1] = (short)f2bf(e0.y);
        xv[2] = (short)f2bf(e0.z); xv[3] = (short)f2bf(e0.w);
        xv[4] = (short)f2bf(e1.x); xv[5] = (short)f2bf(e1.y);
        xv[6] = (short)f2bf(e1.z); xv[7] = (short)f2bf(e1.w);
        int sa = (srow * 512 + sseg * 16) ^ ((srow & 7) << 4);
        *(short8*)&x_raw[sa] = xv;
        __syncthreads();

        short8 af[8];
#pragma unroll
        for (int kt = 0; kt < 8; ++kt) {
            int a = (lr * 512 + kt * 64 + lg * 16) ^ ((lr & 7) << 4);
            af[kt] = *(const short8*)&x_raw[a];
        }
        f32x4 acc[4];
#pragma unroll
        for (int nt = 0; nt < 4; ++nt) {
            acc[nt][0] = bias_l[nt]; acc[nt][1] = bias_l[nt];
            acc[nt][2] = bias_l[nt]; acc[nt][3] = bias_l[nt];
        }
#pragma unroll
        for (int kt = 0; kt < 8; ++kt)
#pragma unroll
            for (int nt = 0; nt < 4; ++nt)
                acc[nt] = __builtin_amdgcn_mfma_f32_16x16x32_bf16(af[kt], bfr[nt][kt], acc[nt], 0, 0, 0);

        ushortT* gp = gin16 + ((size_t)((dir * 4 + g) * CH + (tt0 + i))) * 16384;
#pragma unroll
        for (int nt = 0; nt < 4; ++nt) {
            int col = nt * 256 + ucol;
            us4 st;
            st[0] = f2bf(acc[nt][0]); st[1] = f2bf(acc[nt][1]);
            st[2] = f2bf(acc[nt][2]); st[3] = f2bf(acc[nt][3]);
            *(us4*)(gp + col * 16 + lg * 4) = st;
        }
        __syncthreads();
    }
}

// K-rec: round-10-proven 2-CU mailbox structure (best measured), flat grid 16,
//   register-publish + all-lane spin, hout stores overlapping the spin;
//   gin now bf16 (CH=512 -> single dispatch).
__global__
__attribute__((amdgpu_flat_work_group_size(512, 512)))
__attribute__((amdgpu_waves_per_eu(2, 2)))
void k_rec_mfma(
    const int* __restrict__ lens, const ushortT* __restrict__ whh16,
    const ushortT* __restrict__ gin16, ushortT* __restrict__ hout,
    ushortT* __restrict__ st_h, float* __restrict__ st_c,
    unsigned int* __restrict__ hexu, unsigned int* __restrict__ flags,
    int chunk_start, int CH)
{
    const int bid = blockIdx.x;
    const int half = bid >> 3;
    const int dirg = bid & 7;
    const int g = dirg & 3, dir = dirg >> 2;
    const int gmax = lens[g * 16];
    const int nsteps = min(CH, gmax - chunk_start);
    if (nsteps <= 0) return;

    const int tid = threadIdx.x;
    const int w = tid >> 6, l = tid & 63, lr = l & 15, lg = l >> 4;

    __shared__ char h_s[2][8192];   // [buf][row*512B + unit*2B], XOR-swizzled

    int lenr[4];
#pragma unroll
    for (int r = 0; r < 4; ++r) lenr[r] = lens[g * 16 + lg * 4 + r];

    // weights for this lane's unit column (4 gates x 8 k-tiles); plain loads
    const int ucol = half * 128 + w * 16 + lr;
    short8 bfr[4][8];
    {
        const ushortT* wsrc = whh16 + dir * 262144;
#pragma unroll
        for (int nt = 0; nt < 4; ++nt) {
            const ushortT* wp = wsrc + (size_t)(nt * 256 + ucol) * 256 + lg * 8;
#pragma unroll
            for (int kt = 0; kt < 8; ++kt)
                bfr[nt][kt] = *(const short8*)(wp + kt * 32);
        }
    }

    // state init / restore
    float c[4];
    if (chunk_start == 0) {
#pragma unroll
        for (int r = 0; r < 4; ++r) c[r] = 0.0f;
        for (int i = tid; i < 2048; i += 512) ((int*)h_s[0])[i] = 0;
    } else {
        const float* cs = st_c + ((size_t)(dirg * 2 + half)) * 2048 + tid * 4;
#pragma unroll
        for (int r = 0; r < 4; ++r) c[r] = cs[r];
        const int* hs = (const int*)st_h + dirg * 2048;
        for (int i = tid; i < 2048; i += 512) ((int*)h_s[0])[i] = hs[i];
    }
    __syncthreads();

    // mailbox: exu = 2 slots x 2048 uints per dirg; flags on separate lines
    unsigned int* exu = hexu + dirg * 4096;
    unsigned int* flagMe = flags + dirg * 32 + half * 16;
    unsigned int* flagPeer = flags + dirg * 32 + (half ^ 1) * 16;

    const int pub_base = ucol * 8 + lg * 2;

    int pf_uidx[2], pf_lds0[2], pf_lds1[2];
#pragma unroll
    for (int s2 = 0; s2 < 2; ++s2) {
        int i = tid * 2 + s2;
        int pcol = ((half ^ 1) << 7) + (i >> 3);
        int sub = i & 7;
        pf_uidx[s2] = pcol * 8 + sub;
        int r0 = (sub >> 1) * 4 + (sub & 1) * 2;
        pf_lds0[s2] = (r0 * 512 + pcol * 2) ^ ((r0 & 7) << 4);
        int r1 = r0 + 1;
        pf_lds1[s2] = (r1 * 512 + pcol * 2) ^ ((r1 & 7) << 4);
    }

    const ushortT* ginp = gin16 + (size_t)dirg * CH * 16384;
    int p = 0;
    for (int tt = 0; tt < nsteps; ++tt) {
        const int t_glob = chunk_start + tt;

        // gin (bf16) for my 4 gate-cols; consumed in pointwise
        const ushortT* gb = ginp + (size_t)tt * 16384 + lg * 4;
        us4 gv[4];
#pragma unroll
        for (int nt = 0; nt < 4; ++nt)
            gv[nt] = *(const us4*)(gb + (nt * 256 + ucol) * 16);

        const char* hb = h_s[p];
        f32x4 acc[4];
#pragma unroll
        for (int nt = 0; nt < 4; ++nt) { acc[nt][0] = 0.f; acc[nt][1] = 0.f; acc[nt][2] = 0.f; acc[nt][3] = 0.f; }
#pragma unroll
        for (int kt = 0; kt < 8; ++kt) {
            int a_ = (lr * 512 + kt * 64 + lg * 16) ^ ((lr & 7) << 4);
            short8 af = *(const short8*)&hb[a_];
#pragma unroll
            for (int nt = 0; nt < 4; ++nt)
                acc[nt] = __builtin_amdgcn_mfma_f32_16x16x32_bf16(af, bfr[nt][kt], acc[nt], 0, 0, 0);
        }

        // pointwise; write own LDS; publish from registers
        char* hw = h_s[p ^ 1];
        unsigned int* exs = exu + ((t_glob + 1) & 1) * 2048;
        ushortT hh[4];
#pragma unroll
        for (int r = 0; r < 4; ++r) {
            float i_ = acc[0][r] + bf2f(gv[0][r]);
            float f_ = acc[1][r] + bf2f(gv[1][r]);
            float g_ = acc[2][r] + bf2f(gv[2][r]);
            float o_ = acc[3][r] + bf2f(gv[3][r]);
            float cn = fsig(f_) * c[r] + fsig(i_) * ftanh(g_);
            float hn = fsig(o_) * ftanh(cn);
            c[r] = cn;
            hh[r] = f2bf(hn);
            int row = lg * 4 + r;
            *(ushortT*)&hw[(row * 512 + ucol * 2) ^ ((row & 7) << 4)] = hh[r];
        }
        unsigned int v01 = (unsigned int)hh[0] | ((unsigned int)hh[1] << 16);
        unsigned int v23 = (unsigned int)hh[2] | ((unsigned int)hh[3] << 16);
        __hip_atomic_store(&exs[pub_base + 0], v01, __ATOMIC_RELAXED, __HIP_MEMORY_SCOPE_AGENT);
        __hip_atomic_store(&exs[pub_base + 1], v23, __ATOMIC_RELAXED, __HIP_MEMORY_SCOPE_AGENT);

        __syncthreads();   // drains vmcnt: all lanes' publishes visible

        if (tid == 0)
            __hip_atomic_store(flagMe, (unsigned int)(t_glob + 1), __ATOMIC_RELEASE, __HIP_MEMORY_SCOPE_AGENT);

        // hout stores overlap the spin window
#pragma unroll
        for (int r = 0; r < 4; ++r) {
            if (t_glob < lenr[r]) {
                int row = lg * 4 + r;
                int tp = dir ? (lenr[r] - 1 - t_glob) : t_glob;
                hout[((size_t)((g * 16 + row) * 512 + tp)) * 512 + dir * 256 + ucol] = hh[r];
            }
        }

        {   // all-lane spin (wave-coalesced, same address)
            unsigned int tgt = (unsigned int)(t_glob + 1);
            int guard = 0;
            while (__hip_atomic_load(flagPeer, __ATOMIC_RELAXED, __HIP_MEMORY_SCOPE_AGENT) < tgt
                   && ++guard < (1 << 16)) {}
        }

        // fetch peer half into LDS
#pragma unroll
        for (int s2 = 0; s2 < 2; ++s2) {
            unsigned int v = __hip_atomic_load(&exs[pf_uidx[s2]], __ATOMIC_RELAXED, __HIP_MEMORY_SCOPE_AGENT);
            *(ushortT*)&hw[pf_lds0[s2]] = (ushortT)(v & 0xffffu);
            *(ushortT*)&hw[pf_lds1[s2]] = (ushortT)(v >> 16);
        }
        __syncthreads();
        p ^= 1;
    }

    // save state
    float* cs = st_c + ((size_t)(dirg * 2 + half)) * 2048 + tid * 4;
#pragma unroll
    for (int r = 0; r < 4; ++r) cs[r] = c[r];
    if (half == 0) {
        int* hs = (int*)st_h + dirg * 2048;
        for (int i = tid; i < 2048; i += 512) hs[i] = ((int*)h_s[p])[i];
    }
}

// K-scores: scores[b,t,:] = h[b,t,:] (bf16) @ w_out^T + b_out  (t < len)
__global__ __launch_bounds__(256) void k_scores_bf(
    const int* __restrict__ lens, const ushortT* __restrict__ hout,
    const float* __restrict__ w_out, const float* __restrict__ b_out,
    float* __restrict__ scores)
{
    const int b = blockIdx.y;
    const int t0 = blockIdx.x * 32;
    const int len = lens[b];
    if (t0 >= len) return;

    __shared__ float w_s[20 * 513];
    __shared__ float row_s[512];
    __shared__ float part_s[20][9];
    __shared__ float bo_s[20];

    const int tid = threadIdx.x;
    for (int e = tid; e < 20 * 512; e += 256) w_s[(e >> 9) * 513 + (e & 511)] = w_out[e];
    if (tid < 20) bo_s[tid] = b_out[tid];
    __syncthreads();

    const int tend = min(t0 + 32, len);
    const int tag = tid >> 3, sl = tid & 7;
    for (int t = t0; t < tend; ++t) {
        const ushortT* hr = hout + ((size_t)(b * 512 + t)) * 512;
        unsigned int v = ((const unsigned int*)hr)[tid];
        row_s[tid * 2] = bf2f(v & 0xffffu);
        row_s[tid * 2 + 1] = bf2f(v >> 16);
        __syncthreads();
        if (tid < 160) {
            float s = 0.0f;
#pragma unroll 8
            for (int j = 0; j < 64; ++j) {
                int k = sl + (((j + tag) & 63) << 3);
                s = fmaf(w_s[tag * 513 + k], row_s[k], s);
            }
            part_s[tag][sl] = s;
        }
        __syncthreads();
        if (tid < 20) {
            float s = bo_s[tid];
#pragma unroll
            for (int j = 0; j < 8; ++j) s += part_s[tid][j];
            scores[((size_t)(b * 512 + t)) * 20 + tid] = s;
        }
        __syncthreads();
    }
}

__global__ __launch_bounds__(64) void k_viterbi_s(
    const int* __restrict__ lens, const float* __restrict__ scores,
    const float* __restrict__ trans, float* __restrict__ out)
{
    const int b = blockIdx.x;
    const int lane = threadIdx.x;
    const int len = lens[b];

    __shared__ float tr_s[20][21];
    __shared__ float fv_s[20];
    __shared__ float term_s[20];
    __shared__ unsigned char bp_s[512][20];
    __shared__ unsigned char path_s[512];

    for (int e = lane; e < 400; e += 64) tr_s[e / 20][e % 20] = trans[e];
    if (lane < 20) fv_s[lane] = (lane == TAG_START) ? 0.0f : NEGV;
    __syncthreads();

    const float* sc = scores + ((size_t)(b << 9)) * 20;
    for (int t = 0; t < len; ++t) {
        float m = 0.0f; int arg = 0;
        if (lane < 20) {
            m = fv_s[0] + tr_s[lane][0]; arg = 0;
#pragma unroll
            for (int k = 1; k < 20; ++k) {
                float v = fv_s[k] + tr_s[lane][k];
                if (v > m) { m = v; arg = k; }
            }
            m += sc[t * 20 + lane];
        }
        __syncthreads();
        if (lane < 20) { fv_s[lane] = m; bp_s[t][lane] = (unsigned char)arg; }
        __syncthreads();
    }

    if (lane < 20) term_s[lane] = fv_s[lane] + tr_s[TAG_STOP][lane];
    __syncthreads();

    if (lane == 0) {
        float m = term_s[0]; int arg = 0;
        for (int k = 1; k < 20; ++k) if (term_s[k] > m) { m = term_s[k]; arg = k; }
        out[b] = m;
        int cur = arg;
        path_s[len - 1] = (unsigned char)cur;
        for (int j = len - 1; j >= 1; --j) {
            cur = bp_s[j][cur];
            path_s[j - 1] = (unsigned char)cur;
        }
    }
    __syncthreads();

    float* po = out + NB + ((size_t)b << 9);
    for (int p = lane; p < NL; p += 64) po[p] = (p < len) ? (float)path_s[p] : 0.0f;
}

// ===========================================================================
// FALLBACK PATH (round-2 proven)
// ===========================================================================
__global__ __launch_bounds__(256) void k_transpose_fb(
    const float* __restrict__ whh_f, const float* __restrict__ whh_b,
    const float* __restrict__ wih_f, const float* __restrict__ wih_b,
    float* __restrict__ thh_f, float* __restrict__ thh_b,
    float* __restrict__ tih_f, float* __restrict__ tih_b)
{
    int e = blockIdx.x * 256 + threadIdx.x;
    const float* wm; float* wt;
    switch (blockIdx.y) {
        case 0: wm = whh_f; wt = thh_f; break;
        case 1: wm = whh_b; wt = thh_b; break;
        case 2: wm = wih_f; wt = tih_f; break;
        default: wm = wih_b; wt = tih_b; break;
    }
    int n = e >> 8, k = e & 255;
    wt[k * 1024 + n] = wm[e];
}

__global__ __launch_bounds__(1024) void k_rec_fb(
    const int* __restrict__ sent, const int* __restrict__ lens,
    const float* __restrict__ emb,
    const float* __restrict__ thh_f, const float* __restrict__ thh_b,
    const float* __restrict__ tih_f, const float* __restrict__ tih_b,
    const float* __restrict__ b_ih_f, const float* __restrict__ b_hh_f,
    const float* __restrict__ b_ih_b, const float* __restrict__ b_hh_b,
    const float* __restrict__ w_out,
    float* __restrict__ sc_f, float* __restrict__ sc_b)
{
    const int b = blockIdx.x, dir = blockIdx.y;
    const int len = lens[b];
    const int n = threadIdx.x;
    const float* Whh = dir ? thh_b : thh_f;
    const float* Wih = dir ? tih_b : tih_f;
    const float* bi = dir ? b_ih_b : b_ih_f;
    const float* bh = dir ? b_hh_b : b_hh_f;
    float* scout = dir ? sc_b : sc_f;

    __shared__ float x_s[256];
    __shared__ float h_s[256];
    __shared__ float g_s[1024];
    __shared__ float bias_s[1024];
    __shared__ float wout_s[20 * 257];
    __shared__ float part_s[20][8];

    bias_s[n] = bi[n] + bh[n];
    for (int e = n; e < 20 * 256; e += 1024)
        wout_s[(e >> 8) * 257 + (e & 255)] = w_out[(e >> 8) * 512 + dir * 256 + (e & 255)];
    if (n < 256) h_s[n] = 0.0f;
    float c = 0.0f;
    __syncthreads();

    const int sbase = b << 9;
    for (int t = 0; t < len; ++t) {
        if (n < 256) {
            int ti = dir ? (len - 1 - t) : t;
            int tok = sent[sbase + ti];
            x_s[n] = emb[(size_t)tok * NE + n];
        }
        __syncthreads();
        float acc = bias_s[n];
        const float* wi = Wih + n;
        const float* wh = Whh + n;
#pragma unroll 8
        for (int k = 0; k < 256; ++k) {
            acc = fmaf(wh[(size_t)(k << 10)], h_s[k], acc);
            acc = fmaf(wi[(size_t)(k << 10)], x_s[k], acc);
        }
        g_s[n] = acc;
        __syncthreads();
        if (n < 256) {
            float ig = g_s[n], fg = g_s[n + 256], gg = g_s[n + 512], og = g_s[n + 768];
            float cn = sigf_slow(fg) * c + sigf_slow(ig) * tanhf(gg);
            float hn = sigf_slow(og) * tanhf(cn);
            c = cn; h_s[n] = hn;
        }
        __syncthreads();
        if (n < 160) {
            const int tag = n >> 3, sl = n & 7;
            const float* wrow = wout_s + tag * 257;
            float s = 0.0f;
#pragma unroll 8
            for (int j = 0; j < 32; ++j) { int k = sl + (j << 3); s = fmaf(wrow[k], h_s[k], s); }
            part_s[tag][sl] = s;
        }
        __syncthreads();
        if (n < 20) {
            float s = part_s[n][0];
#pragma unroll
            for (int j = 1; j < 8; ++j) s += part_s[n][j];
            int tp = dir ? (len - 1 - t) : t;
            scout[(size_t)(sbase + tp) * 20 + n] = s;
        }
    }
}

__global__ __launch_bounds__(64) void k_viterbi_fb(
    const int* __restrict__ lens,
    const float* __restrict__ sc_f, const float* __restrict__ sc_b,
    const float* __restrict__ b_out, const float* __restrict__ trans,
    float* __restrict__ out)
{
    const int b = blockIdx.x;
    const int lane = threadIdx.x;
    const int len = lens[b];

    __shared__ float tr_s[20][21];
    __shared__ float fv_s[20];
    __shared__ float term_s[20];
    __shared__ float bo_s[20];
    __shared__ unsigned char bp_s[512][20];
    __shared__ unsigned char path_s[512];

    for (int e = lane; e < 400; e += 64) tr_s[e / 20][e % 20] = trans[e];
    if (lane < 20) { fv_s[lane] = (lane == TAG_START) ? 0.0f : NEGV; bo_s[lane] = b_out[lane]; }
    __syncthreads();

    const size_t sb = (size_t)(b << 9) * 20;
    for (int t = 0; t < len; ++t) {
        float m = 0.0f; int arg = 0;
        if (lane < 20) {
            m = fv_s[0] + tr_s[lane][0]; arg = 0;
#pragma unroll
            for (int k = 1; k < 20; ++k) {
                float v = fv_s[k] + tr_s[lane][k];
                if (v > m) { m = v; arg = k; }
            }
            m += sc_f[sb + t * 20 + lane] + sc_b[sb + t * 20 + lane] + bo_s[lane];
        }
        __syncthreads();
        if (lane < 20) { fv_s[lane] = m; bp_s[t][lane] = (unsigned char)arg; }
        __syncthreads();
    }
    if (lane < 20) term_s[lane] = fv_s[lane] + tr_s[TAG_STOP][lane];
    __syncthreads();
    if (lane == 0) {
        float m = term_s[0]; int arg = 0;
        for (int k = 1; k < 20; ++k) if (term_s[k] > m) { m = term_s[k]; arg = k; }
        out[b] = m;
        int cur = arg;
        path_s[len - 1] = (unsigned char)cur;
        for (int j = len - 1; j >= 1; --j) { cur = bp_s[j][cur]; path_s[j - 1] = (unsigned char)cur; }
    }
    __syncthreads();
    float* po = out + NB + ((size_t)b << 9);
    for (int p = lane; p < NL; p += 64) po[p] = (p < len) ? (float)path_s[p] : 0.0f;
}

// ===========================================================================
extern "C" void kernel_launch(void* const* d_in, const int* in_sizes, int n_in,
                              void* d_out, int out_size, void* d_ws, size_t ws_size,
                              hipStream_t stream)
{
    const int*   sent   = (const int*)d_in[0];
    const int*   lens   = (const int*)d_in[1];
    const float* emb    = (const float*)d_in[2];
    const float* w_ih_f = (const float*)d_in[3];
    const float* w_hh_f = (const float*)d_in[4];
    const float* b_ih_f = (const float*)d_in[5];
    const float* b_hh_f = (const float*)d_in[6];
    const float* w_ih_b = (const float*)d_in[7];
    const float* w_hh_b = (const float*)d_in[8];
    const float* b_ih_b = (const float*)d_in[9];
    const float* b_hh_b = (const float*)d_in[10];
    const float* w_out  = (const float*)d_in[11];
    const float* b_out  = (const float*)d_in[12];
    const float* trans  = (const float*)d_in[13];
    float* out = (float*)d_out;

    char* w = (char*)d_ws;
    // layout:
    //  whh16   @ 0        (1 MB)     wih16 @ 1048576 (1 MB)
    //  biasc   @ 2097152  (8 KB)     st_h  @ 2105344 (64 KB)
    //  st_c    @ 2170880  (128 KB)   hex   @ 2301952 (128 KB)
    //  flags   @ 2433024  (4 KB)     scores@ 2437120 (2.5 MB)
    //  hout    @ 5058560  (32 MB)    gin16 @ 38612992 (CH*256 KB bf16)
    const size_t base = 38612992;
    int CH = 0;
    const int chs[6] = {512, 256, 192, 128, 64, 32};
    for (int i = 0; i < 6; ++i)
        if (base + (size_t)chs[i] * 262144 <= ws_size) { CH = chs[i]; break; }

    if (CH) {
        ushortT* whh16 = (ushortT*)(w);
        ushortT* wih16 = (ushortT*)(w + 1048576);
        float*   biasc = (float*)(w + 2097152);
        ushortT* st_h  = (ushortT*)(w + 2105344);
        float*   st_c  = (float*)(w + 2170880);
        unsigned int* hexu = (unsigned int*)(w + 2301952);
        unsigned int* flags = (unsigned int*)(w + 2433024);
        float*   scores= (float*)(w + 2437120);
        ushortT* hout  = (ushortT*)(w + 5058560);
        ushortT* gin16 = (ushortT*)(w + base);

        hipMemsetAsync(flags, 0, 4096, stream);
        k_cvtw<<<dim3(1024, 4), 256, 0, stream>>>(w_hh_f, w_hh_b, w_ih_f, w_ih_b, whh16, wih16);
        k_bias<<<2, 1024, 0, stream>>>(b_ih_f, b_hh_f, b_ih_b, b_hh_b, biasc);

        for (int cs = 0; cs < NL; cs += CH) {
            k_gin_mfma<<<dim3(4, CH / 16, 4), 512, 0, stream>>>(
                sent, lens, emb, wih16, biasc, gin16, cs, CH);
            k_rec_mfma<<<dim3(16), 512, 0, stream>>>(
                lens, whh16, gin16, hout, st_h, st_c, hexu, flags, cs, CH);
        }
        k_scores_bf<<<dim3(16, 64), 256, 0, stream>>>(lens, hout, w_out, b_out, scores);
        k_viterbi_s<<<64, 64, 0, stream>>>(lens, scores, trans, out);
    } else {
        float* ws2   = (float*)d_ws;
        float* thh_f = ws2;
        float* thh_b = thh_f + 262144;
        float* tih_f = thh_b + 262144;
        float* tih_b = tih_f + 262144;
        float* sc_f  = tih_b + 262144;
        float* sc_b  = sc_f + (size_t)NB * NL * NT;

        k_transpose_fb<<<dim3(1024, 4), 256, 0, stream>>>(
            w_hh_f, w_hh_b, w_ih_f, w_ih_b, thh_f, thh_b, tih_f, tih_b);
        k_rec_fb<<<dim3(NB, 2), 1024, 0, stream>>>(
            sent, lens, emb, thh_f, thh_b, tih_f, tih_b,
            b_ih_f, b_hh_f, b_ih_b, b_hh_b, w_out, sc_f, sc_b);
        k_viterbi_fb<<<NB, 64, 0, stream>>>(lens, sc_f, sc_b, b_out, trans, out);
    }
}